// Round 1
// baseline (184.563 us; speedup 1.0000x reference)
//
#include <hip/hip_runtime.h>
#include <math.h>

// Problem constants
static constexpr int PB = 32;      // batch
static constexpr int PL = 4096;    // seq len
static constexpr int PC = 64;      // in channels
static constexpr int PD = 128;     // out channels
static constexpr int PK = 2048;    // TOPK = L/2

typedef __attribute__((ext_vector_type(8))) short bf16x8;
typedef __attribute__((ext_vector_type(4))) float f32x4;

static constexpr int LSTRIDE = 72; // halfwords per row in LDS W^T (pad 64 -> 72, keeps 16B align)

__device__ inline short f2bf(float f) {
  unsigned u = __float_as_uint(f);
  u += 0x7FFFu + ((u >> 16) & 1u);   // RNE
  return (short)(u >> 16);
}

__device__ inline bf16x8 load_a8(const float* p) {
  float4 f0 = *(const float4*)p;
  float4 f1 = *(const float4*)(p + 4);
  bf16x8 r;
  r[0] = f2bf(f0.x); r[1] = f2bf(f0.y); r[2] = f2bf(f0.z); r[3] = f2bf(f0.w);
  r[4] = f2bf(f1.x); r[5] = f2bf(f1.y); r[6] = f2bf(f1.z); r[7] = f2bf(f1.w);
  return r;
}

// ---------------- kernel 1: scores (B,L) ----------------
// one wave per row: lane c reads x[row,c], butterfly reduce
__global__ __launch_bounds__(256) void scores_kernel(
    const float* __restrict__ x, const float* __restrict__ score_w,
    const float* __restrict__ score_b, float* __restrict__ scores) {
  int lane = threadIdx.x & 63;
  int wid  = threadIdx.x >> 6;
  int row  = blockIdx.x * 4 + wid;               // grid covers B*L/4 exactly
  float v = x[(size_t)row * PC + lane] * score_w[lane];
  #pragma unroll
  for (int off = 32; off; off >>= 1) v += __shfl_xor(v, off);
  if (lane == 0) scores[row] = v + score_b[0];
}

// ---------------- kernel 2: exact top-K selection per batch ----------------
// one block (256 threads) per batch; radix-select over sortable uint keys,
// ties at the threshold broken by lowest index (matches lax.top_k).
__global__ __launch_bounds__(256) void select_kernel(
    const float* __restrict__ scores, int* __restrict__ selidx) {
  __shared__ unsigned keys[PL];      // 16 KB
  __shared__ unsigned hist[256];
  __shared__ unsigned sbuf[256];
  __shared__ unsigned sh_prefix, sh_need;

  int tid = threadIdx.x;
  int b = blockIdx.x;
  const float* sc = scores + (size_t)b * PL;

  for (int i = tid; i < PL; i += 256) {
    unsigned u = __float_as_uint(sc[i]);
    keys[i] = (u & 0x80000000u) ? ~u : (u | 0x80000000u);  // order-preserving
  }
  if (tid == 0) { sh_prefix = 0u; sh_need = (unsigned)PK; }
  __syncthreads();

  // 4 radix rounds, MSB first
  for (int r = 3; r >= 0; --r) {
    int shift = r * 8;
    hist[tid] = 0u;
    __syncthreads();
    unsigned prefix = sh_prefix;
    unsigned maskAbove = (r == 3) ? 0u : (~0u << (shift + 8));
    for (int i = tid; i < PL; i += 256) {
      unsigned k = keys[i];
      if ((k & maskAbove) == prefix)
        atomicAdd(&hist[(k >> shift) & 255u], 1u);
    }
    __syncthreads();
    if (tid == 0) {
      unsigned need = sh_need, cum = 0;
      int d = 255;
      for (; d >= 0; --d) {
        if (cum + hist[d] >= need) break;
        cum += hist[d];
      }
      sh_prefix = prefix | ((unsigned)d << shift);
      sh_need = need - cum;
    }
    __syncthreads();
  }
  unsigned T = sh_prefix;       // K-th largest key
  unsigned needEq = sh_need;    // how many ==T to take (lowest indices)

  // each thread owns 16 contiguous indices
  int base = tid * 16;
  unsigned ceq = 0;
  for (int j = 0; j < 16; ++j) ceq += (keys[base + j] == T);

  // exclusive scan of eq counts
  sbuf[tid] = ceq; __syncthreads();
  for (int off = 1; off < 256; off <<= 1) {
    unsigned t = (tid >= off) ? sbuf[tid - off] : 0u;
    __syncthreads();
    sbuf[tid] += t;
    __syncthreads();
  }
  unsigned eqbase = sbuf[tid] - ceq;
  __syncthreads();

  // count selected in my chunk
  unsigned csel = 0, eqr = eqbase;
  for (int j = 0; j < 16; ++j) {
    unsigned k = keys[base + j];
    if (k > T) csel++;
    else if (k == T) { if (eqr < needEq) csel++; eqr++; }
  }
  sbuf[tid] = csel; __syncthreads();
  for (int off = 1; off < 256; off <<= 1) {
    unsigned t = (tid >= off) ? sbuf[tid - off] : 0u;
    __syncthreads();
    sbuf[tid] += t;
    __syncthreads();
  }
  unsigned pos = sbuf[tid] - csel;
  // write compacted indices
  eqr = eqbase;
  int* outp = selidx + (size_t)b * PK;
  for (int j = 0; j < 16; ++j) {
    unsigned k = keys[base + j];
    bool sel;
    if (k > T) sel = true;
    else if (k == T) { sel = (eqr < needEq); eqr++; }
    else sel = false;
    if (sel) outp[pos++] = base + j;
  }
}

// ---------------- shared staging: W^T (C x D fp32) -> LDS bf16 [D][LSTRIDE] ----
__device__ inline void stage_wt(const float* __restrict__ w, short* WT, int tid) {
  // 4096 c-pairs: i -> d = i&127, cpair = i>>7
  for (int i = tid; i < (PC / 2) * PD; i += 256) {
    int d = i & (PD - 1);
    int cp = i >> 7;
    float a = w[(size_t)(2 * cp) * PD + d];
    float c = w[(size_t)(2 * cp + 1) * PD + d];
    unsigned lo = (unsigned short)f2bf(a);
    unsigned hi = (unsigned short)f2bf(c);
    ((unsigned*)WT)[d * (LSTRIDE / 2) + cp] = lo | (hi << 16);
  }
}

// ---------------- kernel 3: sparse GEMM + gelu + sum into agg ----------------
// block = 256 = 4 waves; each wave: 16 selected rows x 128 cols via MFMA
__global__ __launch_bounds__(256) void sparse_kernel(
    const float* __restrict__ x, const float* __restrict__ sparse_w,
    const float* __restrict__ sparse_b, const int* __restrict__ selidx,
    float* __restrict__ agg) {
  __shared__ short WT[PD * LSTRIDE];
  __shared__ float red[PD];
  int tid = threadIdx.x;
  stage_wt(sparse_w, WT, tid);
  if (tid < PD) red[tid] = 0.f;
  __syncthreads();

  int lane = tid & 63, wid = tid >> 6;
  int ln = lane & 15, quad = lane >> 4;
  int b  = blockIdx.x >> 5;            // 32 row-blocks per batch
  int rb = blockIdx.x & 31;
  int j  = rb * 64 + wid * 16 + ln;    // selected slot
  int row = selidx[(size_t)b * PK + j];

  const float* ap = x + ((size_t)b * PL + row) * PC + quad * 8;
  bf16x8 a0 = load_a8(ap);
  bf16x8 a1 = load_a8(ap + 32);

  f32x4 acc[8];
  #pragma unroll
  for (int t = 0; t < 8; ++t) acc[t] = (f32x4){0.f, 0.f, 0.f, 0.f};

  #pragma unroll
  for (int t = 0; t < 8; ++t) {
    const short* wp = WT + (t * 16 + ln) * LSTRIDE + quad * 8;
    bf16x8 b0 = *(const bf16x8*)wp;
    bf16x8 b1 = *(const bf16x8*)(wp + 32);
    acc[t] = __builtin_amdgcn_mfma_f32_16x16x32_bf16(a0, b0, acc[t], 0, 0, 0);
    acc[t] = __builtin_amdgcn_mfma_f32_16x16x32_bf16(a1, b1, acc[t], 0, 0, 0);
  }

  // gelu(feat + bias), sum over this wave's 16 rows per column
  #pragma unroll
  for (int t = 0; t < 8; ++t) {
    float bias = sparse_b[t * 16 + ln];
    float s = 0.f;
    #pragma unroll
    for (int i = 0; i < 4; ++i) {
      float v = acc[t][i] + bias;
      s += 0.5f * v * (1.0f + erff(v * 0.70710678118654752f));
    }
    s += __shfl_xor(s, 16);
    s += __shfl_xor(s, 32);     // now sum over all 16 rows of the wave
    if (quad == 0) atomicAdd(&red[t * 16 + ln], s);
  }
  __syncthreads();
  if (tid < PD) atomicAdd(&agg[(size_t)b * PD + tid], red[tid]);
}

// ---------------- kernel 4: full GEMM + agg + LayerNorm + store -------------
__global__ __launch_bounds__(256) void full_ln_kernel(
    const float* __restrict__ x, const float* __restrict__ full_w,
    const float* __restrict__ full_b, const float* __restrict__ ln_g,
    const float* __restrict__ ln_b, const float* __restrict__ agg,
    float* __restrict__ out) {
  __shared__ short WT[PD * LSTRIDE];
  int tid = threadIdx.x;
  stage_wt(full_w, WT, tid);
  __syncthreads();

  int lane = tid & 63, wid = tid >> 6;
  int ln = lane & 15, quad = lane >> 4;
  int rowbase = blockIdx.x * 64 + wid * 16;   // 16 rows per wave
  int b = rowbase >> 12;                       // L = 4096

  const float invK = 1.0f / (float)PK;
  float bias[8], gg[8], bb[8];
  #pragma unroll
  for (int t = 0; t < 8; ++t) {
    int d = t * 16 + ln;
    bias[t] = full_b[d] + agg[(size_t)b * PD + d] * invK;
    gg[t] = ln_g[d];
    bb[t] = ln_b[d];
  }

  int arow = rowbase + ln;
  const float* ap = x + (size_t)arow * PC + quad * 8;
  bf16x8 a0 = load_a8(ap);
  bf16x8 a1 = load_a8(ap + 32);

  f32x4 acc[8];
  #pragma unroll
  for (int t = 0; t < 8; ++t) acc[t] = (f32x4){0.f, 0.f, 0.f, 0.f};

  #pragma unroll
  for (int t = 0; t < 8; ++t) {
    const short* wp = WT + (t * 16 + ln) * LSTRIDE + quad * 8;
    bf16x8 b0 = *(const bf16x8*)wp;
    bf16x8 b1 = *(const bf16x8*)(wp + 32);
    acc[t] = __builtin_amdgcn_mfma_f32_16x16x32_bf16(a0, b0, acc[t], 0, 0, 0);
    acc[t] = __builtin_amdgcn_mfma_f32_16x16x32_bf16(a1, b1, acc[t], 0, 0, 0);
  }

  // h = feat + bias; LayerNorm per row (row = rowbase + quad*4 + i,
  // its 128 cols live on the 16 lanes of this quad x 8 tiles)
  float s[4] = {0.f, 0.f, 0.f, 0.f}, ss[4] = {0.f, 0.f, 0.f, 0.f};
  #pragma unroll
  for (int t = 0; t < 8; ++t) {
    #pragma unroll
    for (int i = 0; i < 4; ++i) {
      float h = acc[t][i] + bias[t];
      acc[t][i] = h;
      s[i] += h;
      ss[i] += h * h;
    }
  }
  #pragma unroll
  for (int i = 0; i < 4; ++i) {
    #pragma unroll
    for (int off = 1; off < 16; off <<= 1) {
      s[i]  += __shfl_xor(s[i], off);
      ss[i] += __shfl_xor(ss[i], off);
    }
  }
  float mu[4], inv[4];
  #pragma unroll
  for (int i = 0; i < 4; ++i) {
    mu[i] = s[i] * (1.0f / 128.0f);
    float var = ss[i] * (1.0f / 128.0f) - mu[i] * mu[i];
    inv[i] = rsqrtf(var + 1e-5f);
  }
  #pragma unroll
  for (int t = 0; t < 8; ++t) {
    #pragma unroll
    for (int i = 0; i < 4; ++i) {
      int r = rowbase + quad * 4 + i;
      out[(size_t)r * PD + t * 16 + ln] = (acc[t][i] - mu[i]) * inv[i] * gg[t] + bb[t];
    }
  }
}

// ---------------- launcher ----------------
extern "C" void kernel_launch(void* const* d_in, const int* in_sizes, int n_in,
                              void* d_out, int out_size, void* d_ws, size_t ws_size,
                              hipStream_t stream) {
  const float* x        = (const float*)d_in[0];
  const float* score_w  = (const float*)d_in[1];
  const float* score_b  = (const float*)d_in[2];
  const float* sparse_w = (const float*)d_in[3];
  const float* sparse_b = (const float*)d_in[4];
  const float* full_w   = (const float*)d_in[5];
  const float* full_b   = (const float*)d_in[6];
  const float* ln_g     = (const float*)d_in[7];
  const float* ln_b     = (const float*)d_in[8];
  float* out = (float*)d_out;

  float* scores = (float*)d_ws;                                  // B*L f32
  int*   selidx = (int*)((char*)d_ws + (size_t)PB * PL * 4);     // B*K i32
  float* agg    = (float*)((char*)d_ws + (size_t)PB * PL * 4 + (size_t)PB * PK * 4); // B*D f32

  hipMemsetAsync(agg, 0, (size_t)PB * PD * sizeof(float), stream);
  scores_kernel<<<PB * PL / 4, 256, 0, stream>>>(x, score_w, score_b, scores);
  select_kernel<<<PB, 256, 0, stream>>>(scores, selidx);
  sparse_kernel<<<PB * (PK / 64), 256, 0, stream>>>(x, sparse_w, sparse_b, selidx, agg);
  full_ln_kernel<<<PB * PL / 64, 256, 0, stream>>>(x, full_w, full_b, ln_g, ln_b, agg, out);
}

// Round 2
// 152.249 us; speedup vs baseline: 1.2122x; 1.2122x over previous
//
#include <hip/hip_runtime.h>
#include <math.h>

// Problem constants
static constexpr int PB = 32;      // batch
static constexpr int PL = 4096;    // seq len
static constexpr int PC = 64;      // in channels
static constexpr int PD = 128;     // out channels
static constexpr int PK = 2048;    // TOPK = L/2

typedef __attribute__((ext_vector_type(8))) short bf16x8;
typedef __attribute__((ext_vector_type(4))) float f32x4;

static constexpr int LSTRIDE = 72; // halfwords per row in LDS W^T (pad 64 -> 72, keeps 16B align)

__device__ inline short f2bf(float f) {
  unsigned u = __float_as_uint(f);
  u += 0x7FFFu + ((u >> 16) & 1u);   // RNE
  return (short)(u >> 16);
}

__device__ inline bf16x8 load_a8(const float* p) {
  float4 f0 = *(const float4*)p;
  float4 f1 = *(const float4*)(p + 4);
  bf16x8 r;
  r[0] = f2bf(f0.x); r[1] = f2bf(f0.y); r[2] = f2bf(f0.z); r[3] = f2bf(f0.w);
  r[4] = f2bf(f1.x); r[5] = f2bf(f1.y); r[6] = f2bf(f1.z); r[7] = f2bf(f1.w);
  return r;
}

// ---------------- kernel 1: scores (B,L) ----------------
// one wave per row: lane c reads x[row,c], butterfly reduce
__global__ __launch_bounds__(256) void scores_kernel(
    const float* __restrict__ x, const float* __restrict__ score_w,
    const float* __restrict__ score_b, float* __restrict__ scores) {
  int lane = threadIdx.x & 63;
  int wid  = threadIdx.x >> 6;
  int row  = blockIdx.x * 4 + wid;               // grid covers B*L/4 exactly
  float v = x[(size_t)row * PC + lane] * score_w[lane];
  #pragma unroll
  for (int off = 32; off; off >>= 1) v += __shfl_xor(v, off);
  if (lane == 0) scores[row] = v + score_b[0];
}

// ---------------- kernel 2: exact top-K selection per batch ----------------
// one block (256 threads) per batch; radix-select over sortable uint keys,
// ties at the threshold broken by lowest index (matches lax.top_k).
// R1: digit search is a PARALLEL suffix-scan (the R0 serial thread-0 walk of
// 256 LDS buckets was a ~120cyc-dependent-load chain = the whole 50 us).
__global__ __launch_bounds__(256) void select_kernel(
    const float* __restrict__ scores, int* __restrict__ selidx) {
  __shared__ unsigned keys[PL];      // 16 KB
  __shared__ unsigned hist[256];
  __shared__ unsigned sbuf[257];
  __shared__ unsigned sh_prefix, sh_need;

  int tid = threadIdx.x;
  int b = blockIdx.x;
  const float* sc = scores + (size_t)b * PL;

  for (int i = tid; i < PL; i += 256) {
    unsigned u = __float_as_uint(sc[i]);
    keys[i] = (u & 0x80000000u) ? ~u : (u | 0x80000000u);  // order-preserving
  }
  if (tid == 0) { sh_prefix = 0u; sh_need = (unsigned)PK; sbuf[256] = 0u; }
  __syncthreads();

  // 4 radix rounds, MSB first
  for (int r = 3; r >= 0; --r) {
    int shift = r * 8;
    hist[tid] = 0u;
    __syncthreads();
    unsigned prefix = sh_prefix;
    unsigned need   = sh_need;
    unsigned maskAbove = (r == 3) ? 0u : (~0u << (shift + 8));
    for (int i = tid; i < PL; i += 256) {
      unsigned k = keys[i];
      if ((k & maskAbove) == prefix)
        atomicAdd(&hist[(k >> shift) & 255u], 1u);
    }
    __syncthreads();
    // parallel suffix sum: sbuf[d] = sum_{d' >= d} hist[d']
    sbuf[tid] = hist[tid];
    __syncthreads();
    #pragma unroll
    for (int off = 1; off < 256; off <<= 1) {
      unsigned t = (tid + off < 256) ? sbuf[tid + off] : 0u;
      __syncthreads();
      sbuf[tid] += t;
      __syncthreads();
    }
    // suffix is non-increasing; unique boundary d: suffix[d]>=need, suffix[d+1]<need
    if (sbuf[tid] >= need && sbuf[tid + 1] < need) {
      sh_prefix = prefix | ((unsigned)tid << shift);
      sh_need = need - sbuf[tid + 1];
    }
    __syncthreads();
  }
  unsigned T = sh_prefix;       // K-th largest key
  unsigned needEq = sh_need;    // how many ==T to take (lowest indices)

  // each thread owns 16 contiguous indices
  int base = tid * 16;
  unsigned ceq = 0;
  for (int j = 0; j < 16; ++j) ceq += (keys[base + j] == T);

  // exclusive scan of eq counts
  sbuf[tid] = ceq; __syncthreads();
  for (int off = 1; off < 256; off <<= 1) {
    unsigned t = (tid >= off) ? sbuf[tid - off] : 0u;
    __syncthreads();
    sbuf[tid] += t;
    __syncthreads();
  }
  unsigned eqbase = sbuf[tid] - ceq;
  __syncthreads();

  // count selected in my chunk
  unsigned csel = 0, eqr = eqbase;
  for (int j = 0; j < 16; ++j) {
    unsigned k = keys[base + j];
    if (k > T) csel++;
    else if (k == T) { if (eqr < needEq) csel++; eqr++; }
  }
  sbuf[tid] = csel; __syncthreads();
  for (int off = 1; off < 256; off <<= 1) {
    unsigned t = (tid >= off) ? sbuf[tid - off] : 0u;
    __syncthreads();
    sbuf[tid] += t;
    __syncthreads();
  }
  unsigned pos = sbuf[tid] - csel;
  // write compacted indices
  eqr = eqbase;
  int* outp = selidx + (size_t)b * PK;
  for (int j = 0; j < 16; ++j) {
    unsigned k = keys[base + j];
    bool sel;
    if (k > T) sel = true;
    else if (k == T) { sel = (eqr < needEq); eqr++; }
    else sel = false;
    if (sel) outp[pos++] = base + j;
  }
}

// ---------------- shared staging: W^T (C x D fp32) -> LDS bf16 [D][LSTRIDE] ----
__device__ inline void stage_wt(const float* __restrict__ w, short* WT, int tid) {
  // 4096 c-pairs: i -> d = i&127, cpair = i>>7
  for (int i = tid; i < (PC / 2) * PD; i += 256) {
    int d = i & (PD - 1);
    int cp = i >> 7;
    float a = w[(size_t)(2 * cp) * PD + d];
    float c = w[(size_t)(2 * cp + 1) * PD + d];
    unsigned lo = (unsigned short)f2bf(a);
    unsigned hi = (unsigned short)f2bf(c);
    ((unsigned*)WT)[d * (LSTRIDE / 2) + cp] = lo | (hi << 16);
  }
}

// ---------------- kernel 3: sparse GEMM + gelu + sum into agg ----------------
// block = 256 = 4 waves; each wave: 16 selected rows x 128 cols via MFMA
__global__ __launch_bounds__(256) void sparse_kernel(
    const float* __restrict__ x, const float* __restrict__ sparse_w,
    const float* __restrict__ sparse_b, const int* __restrict__ selidx,
    float* __restrict__ agg) {
  __shared__ short WT[PD * LSTRIDE];
  __shared__ float red[PD];
  int tid = threadIdx.x;
  stage_wt(sparse_w, WT, tid);
  if (tid < PD) red[tid] = 0.f;
  __syncthreads();

  int lane = tid & 63, wid = tid >> 6;
  int ln = lane & 15, quad = lane >> 4;
  int b  = blockIdx.x >> 5;            // 32 row-blocks per batch
  int rb = blockIdx.x & 31;
  int j  = rb * 64 + wid * 16 + ln;    // selected slot
  int row = selidx[(size_t)b * PK + j];

  const float* ap = x + ((size_t)b * PL + row) * PC + quad * 8;
  bf16x8 a0 = load_a8(ap);
  bf16x8 a1 = load_a8(ap + 32);

  f32x4 acc[8];
  #pragma unroll
  for (int t = 0; t < 8; ++t) acc[t] = (f32x4){0.f, 0.f, 0.f, 0.f};

  #pragma unroll
  for (int t = 0; t < 8; ++t) {
    const short* wp = WT + (t * 16 + ln) * LSTRIDE + quad * 8;
    bf16x8 b0 = *(const bf16x8*)wp;
    bf16x8 b1 = *(const bf16x8*)(wp + 32);
    acc[t] = __builtin_amdgcn_mfma_f32_16x16x32_bf16(a0, b0, acc[t], 0, 0, 0);
    acc[t] = __builtin_amdgcn_mfma_f32_16x16x32_bf16(a1, b1, acc[t], 0, 0, 0);
  }

  // gelu(feat + bias), sum over this wave's 16 rows per column
  #pragma unroll
  for (int t = 0; t < 8; ++t) {
    float bias = sparse_b[t * 16 + ln];
    float s = 0.f;
    #pragma unroll
    for (int i = 0; i < 4; ++i) {
      float v = acc[t][i] + bias;
      s += 0.5f * v * (1.0f + erff(v * 0.70710678118654752f));
    }
    s += __shfl_xor(s, 16);
    s += __shfl_xor(s, 32);     // now sum over all 16 rows of the wave
    if (quad == 0) atomicAdd(&red[t * 16 + ln], s);
  }
  __syncthreads();
  if (tid < PD) atomicAdd(&agg[(size_t)b * PD + tid], red[tid]);
}

// ---------------- kernel 4: full GEMM + agg + LayerNorm + store -------------
__global__ __launch_bounds__(256) void full_ln_kernel(
    const float* __restrict__ x, const float* __restrict__ full_w,
    const float* __restrict__ full_b, const float* __restrict__ ln_g,
    const float* __restrict__ ln_b, const float* __restrict__ agg,
    float* __restrict__ out) {
  __shared__ short WT[PD * LSTRIDE];
  int tid = threadIdx.x;
  stage_wt(full_w, WT, tid);
  __syncthreads();

  int lane = tid & 63, wid = tid >> 6;
  int ln = lane & 15, quad = lane >> 4;
  int rowbase = blockIdx.x * 64 + wid * 16;   // 16 rows per wave
  int b = rowbase >> 12;                       // L = 4096

  const float invK = 1.0f / (float)PK;
  float bias[8], gg[8], bb[8];
  #pragma unroll
  for (int t = 0; t < 8; ++t) {
    int d = t * 16 + ln;
    bias[t] = full_b[d] + agg[(size_t)b * PD + d] * invK;
    gg[t] = ln_g[d];
    bb[t] = ln_b[d];
  }

  int arow = rowbase + ln;
  const float* ap = x + (size_t)arow * PC + quad * 8;
  bf16x8 a0 = load_a8(ap);
  bf16x8 a1 = load_a8(ap + 32);

  f32x4 acc[8];
  #pragma unroll
  for (int t = 0; t < 8; ++t) acc[t] = (f32x4){0.f, 0.f, 0.f, 0.f};

  #pragma unroll
  for (int t = 0; t < 8; ++t) {
    const short* wp = WT + (t * 16 + ln) * LSTRIDE + quad * 8;
    bf16x8 b0 = *(const bf16x8*)wp;
    bf16x8 b1 = *(const bf16x8*)(wp + 32);
    acc[t] = __builtin_amdgcn_mfma_f32_16x16x32_bf16(a0, b0, acc[t], 0, 0, 0);
    acc[t] = __builtin_amdgcn_mfma_f32_16x16x32_bf16(a1, b1, acc[t], 0, 0, 0);
  }

  // h = feat + bias; LayerNorm per row (row = rowbase + quad*4 + i,
  // its 128 cols live on the 16 lanes of this quad x 8 tiles)
  float s[4] = {0.f, 0.f, 0.f, 0.f}, ss[4] = {0.f, 0.f, 0.f, 0.f};
  #pragma unroll
  for (int t = 0; t < 8; ++t) {
    #pragma unroll
    for (int i = 0; i < 4; ++i) {
      float h = acc[t][i] + bias[t];
      acc[t][i] = h;
      s[i] += h;
      ss[i] += h * h;
    }
  }
  #pragma unroll
  for (int i = 0; i < 4; ++i) {
    #pragma unroll
    for (int off = 1; off < 16; off <<= 1) {
      s[i]  += __shfl_xor(s[i], off);
      ss[i] += __shfl_xor(ss[i], off);
    }
  }
  float mu[4], inv[4];
  #pragma unroll
  for (int i = 0; i < 4; ++i) {
    mu[i] = s[i] * (1.0f / 128.0f);
    float var = ss[i] * (1.0f / 128.0f) - mu[i] * mu[i];
    inv[i] = rsqrtf(var + 1e-5f);
  }
  #pragma unroll
  for (int t = 0; t < 8; ++t) {
    #pragma unroll
    for (int i = 0; i < 4; ++i) {
      int r = rowbase + quad * 4 + i;
      out[(size_t)r * PD + t * 16 + ln] = (acc[t][i] - mu[i]) * inv[i] * gg[t] + bb[t];
    }
  }
}

// ---------------- launcher ----------------
extern "C" void kernel_launch(void* const* d_in, const int* in_sizes, int n_in,
                              void* d_out, int out_size, void* d_ws, size_t ws_size,
                              hipStream_t stream) {
  const float* x        = (const float*)d_in[0];
  const float* score_w  = (const float*)d_in[1];
  const float* score_b  = (const float*)d_in[2];
  const float* sparse_w = (const float*)d_in[3];
  const float* sparse_b = (const float*)d_in[4];
  const float* full_w   = (const float*)d_in[5];
  const float* full_b   = (const float*)d_in[6];
  const float* ln_g     = (const float*)d_in[7];
  const float* ln_b     = (const float*)d_in[8];
  float* out = (float*)d_out;

  float* scores = (float*)d_ws;                                  // B*L f32
  int*   selidx = (int*)((char*)d_ws + (size_t)PB * PL * 4);     // B*K i32
  float* agg    = (float*)((char*)d_ws + (size_t)PB * PL * 4 + (size_t)PB * PK * 4); // B*D f32

  hipMemsetAsync(agg, 0, (size_t)PB * PD * sizeof(float), stream);
  scores_kernel<<<PB * PL / 4, 256, 0, stream>>>(x, score_w, score_b, scores);
  select_kernel<<<PB, 256, 0, stream>>>(scores, selidx);
  sparse_kernel<<<PB * (PK / 64), 256, 0, stream>>>(x, sparse_w, sparse_b, selidx, agg);
  full_ln_kernel<<<PB * PL / 64, 256, 0, stream>>>(x, full_w, full_b, ln_g, ln_b, agg, out);
}

// Round 3
// 138.124 us; speedup vs baseline: 1.3362x; 1.1023x over previous
//
#include <hip/hip_runtime.h>
#include <math.h>

// Problem constants
static constexpr int PB = 32;      // batch
static constexpr int PL = 4096;    // seq len
static constexpr int PC = 64;      // in channels
static constexpr int PD = 128;     // out channels
static constexpr int PK = 2048;    // TOPK = L/2

typedef __attribute__((ext_vector_type(8))) short bf16x8;
typedef __attribute__((ext_vector_type(4))) float f32x4;

static constexpr int LSTRIDE = 72; // halfwords per row in LDS W^T (pad 64 -> 72, keeps 16B align)

__device__ inline short f2bf(float f) {
  unsigned u = __float_as_uint(f);
  u += 0x7FFFu + ((u >> 16) & 1u);   // RNE
  return (short)(u >> 16);
}

__device__ inline bf16x8 load_a8(const float* p) {
  float4 f0 = *(const float4*)p;
  float4 f1 = *(const float4*)(p + 4);
  bf16x8 r;
  r[0] = f2bf(f0.x); r[1] = f2bf(f0.y); r[2] = f2bf(f0.z); r[3] = f2bf(f0.w);
  r[4] = f2bf(f1.x); r[5] = f2bf(f1.y); r[6] = f2bf(f1.z); r[7] = f2bf(f1.w);
  return r;
}

// ---------------- kernel 1: scores (B,L) ----------------
// R3: float4 loads (16 B/lane). Block = 256 threads = 16 rows;
// thread tid: row r = tid>>4, channel-quad c4 = tid&15.
__global__ __launch_bounds__(256) void scores_kernel(
    const float* __restrict__ x, const float* __restrict__ score_w,
    const float* __restrict__ score_b, float* __restrict__ scores) {
  int tid = threadIdx.x;
  int r  = tid >> 4;
  int c4 = tid & 15;
  int row = blockIdx.x * 16 + r;                 // grid covers B*L/16 exactly
  float4 xv = *(const float4*)(x + (size_t)row * PC + c4 * 4);
  float4 wv = *(const float4*)(score_w + c4 * 4);
  float v = xv.x * wv.x + xv.y * wv.y + xv.z * wv.z + xv.w * wv.w;
  #pragma unroll
  for (int off = 1; off < 16; off <<= 1) v += __shfl_xor(v, off);
  if (c4 == 0) scores[row] = v + score_b[0];
}

// ---------------- kernel 2: exact top-K selection per batch ----------------
// one block (256 threads = 4 waves) per batch; radix-select over sortable uint
// keys, ties at threshold broken by lowest index (matches lax.top_k).
// R3: all 256-element scans are wave-level __shfl scans (no LDS barriers per
// step) + one cross-wave combine — barrier count ~112 -> ~26.
// Also zeroes agg[b*D..] (select runs before sparse; ws is re-poisoned 0xAA).
__global__ __launch_bounds__(256) void select_kernel(
    const float* __restrict__ scores, int* __restrict__ selidx,
    float* __restrict__ agg) {
  __shared__ unsigned keys[PL];      // 16 KB
  __shared__ unsigned hist[256];
  __shared__ unsigned sbuf[257];
  __shared__ unsigned wsum[4];
  __shared__ unsigned sh_prefix, sh_need;

  int tid = threadIdx.x;
  int lane = tid & 63;
  int wid  = tid >> 6;
  int b = blockIdx.x;
  const float* sc = scores + (size_t)b * PL;

  for (int i = tid; i < PL; i += 256) {
    unsigned u = __float_as_uint(sc[i]);
    keys[i] = (u & 0x80000000u) ? ~u : (u | 0x80000000u);  // order-preserving
  }
  if (tid == 0) { sh_prefix = 0u; sh_need = (unsigned)PK; sbuf[256] = 0u; }
  // zero agg for this batch (sparse_kernel accumulates into it later)
  if (tid < PD) agg[(size_t)b * PD + tid] = 0.f;
  __syncthreads();

  // 4 radix rounds, MSB first
  for (int r = 3; r >= 0; --r) {
    int shift = r * 8;
    hist[tid] = 0u;
    __syncthreads();                      // also publishes sh_prefix/sh_need
    unsigned prefix = sh_prefix;
    unsigned need   = sh_need;
    unsigned maskAbove = (r == 3) ? 0u : (~0u << (shift + 8));
    for (int i = tid; i < PL; i += 256) {
      unsigned k = keys[i];
      if ((k & maskAbove) == prefix)
        atomicAdd(&hist[(k >> shift) & 255u], 1u);
    }
    __syncthreads();
    // inclusive suffix sum of hist via wave shfl (bucket = tid)
    unsigned v = hist[tid];
    #pragma unroll
    for (int off = 1; off < 64; off <<= 1) {
      unsigned t = __shfl_down(v, off);
      if (lane + off < 64) v += t;
    }
    if (lane == 0) wsum[wid] = v;         // sum of this wave's 64 buckets
    __syncthreads();
    unsigned add = 0;
    #pragma unroll
    for (int w = 0; w < 4; ++w) if (w > wid) add += wsum[w];
    sbuf[tid] = v + add;
    __syncthreads();
    // suffix non-increasing; unique boundary: sbuf[d]>=need, sbuf[d+1]<need
    if (sbuf[tid] >= need && sbuf[tid + 1] < need) {
      sh_prefix = prefix | ((unsigned)tid << shift);
      sh_need = need - sbuf[tid + 1];
    }
  }
  __syncthreads();
  unsigned T = sh_prefix;       // K-th largest key
  unsigned needEq = sh_need;    // how many ==T to take (lowest indices)

  // each thread owns 16 contiguous indices
  int base = tid * 16;
  unsigned ceq = 0;
  #pragma unroll
  for (int j = 0; j < 16; ++j) ceq += (keys[base + j] == T);

  // exclusive prefix scan of eq counts (wave shfl + cross-wave)
  unsigned v1 = ceq;
  #pragma unroll
  for (int off = 1; off < 64; off <<= 1) {
    unsigned t = __shfl_up(v1, off);
    if (lane >= off) v1 += t;
  }
  if (lane == 63) wsum[wid] = v1;
  __syncthreads();
  unsigned add1 = 0;
  #pragma unroll
  for (int w = 0; w < 4; ++w) if (w < wid) add1 += wsum[w];
  unsigned eqbase = v1 + add1 - ceq;
  __syncthreads();                        // protect wsum before reuse

  // count selected in my chunk
  unsigned csel = 0, eqr = eqbase;
  #pragma unroll
  for (int j = 0; j < 16; ++j) {
    unsigned k = keys[base + j];
    if (k > T) csel++;
    else if (k == T) { if (eqr < needEq) csel++; eqr++; }
  }
  unsigned v2 = csel;
  #pragma unroll
  for (int off = 1; off < 64; off <<= 1) {
    unsigned t = __shfl_up(v2, off);
    if (lane >= off) v2 += t;
  }
  if (lane == 63) wsum[wid] = v2;
  __syncthreads();
  unsigned add2 = 0;
  #pragma unroll
  for (int w = 0; w < 4; ++w) if (w < wid) add2 += wsum[w];
  unsigned pos = v2 + add2 - csel;

  // write compacted indices
  eqr = eqbase;
  int* outp = selidx + (size_t)b * PK;
  #pragma unroll
  for (int j = 0; j < 16; ++j) {
    unsigned k = keys[base + j];
    bool sel;
    if (k > T) sel = true;
    else if (k == T) { sel = (eqr < needEq); eqr++; }
    else sel = false;
    if (sel) outp[pos++] = base + j;
  }
}

// ---------------- shared staging: W^T (C x D fp32) -> LDS bf16 [D][LSTRIDE] ----
__device__ inline void stage_wt(const float* __restrict__ w, short* WT, int tid) {
  // 4096 c-pairs: i -> d = i&127, cpair = i>>7
  for (int i = tid; i < (PC / 2) * PD; i += 256) {
    int d = i & (PD - 1);
    int cp = i >> 7;
    float a = w[(size_t)(2 * cp) * PD + d];
    float c = w[(size_t)(2 * cp + 1) * PD + d];
    unsigned lo = (unsigned short)f2bf(a);
    unsigned hi = (unsigned short)f2bf(c);
    ((unsigned*)WT)[d * (LSTRIDE / 2) + cp] = lo | (hi << 16);
  }
}

// ---------------- kernel 3: sparse GEMM + gelu + sum into agg ----------------
// block = 256 = 4 waves; each wave: 16 selected rows x 128 cols via MFMA
__global__ __launch_bounds__(256) void sparse_kernel(
    const float* __restrict__ x, const float* __restrict__ sparse_w,
    const float* __restrict__ sparse_b, const int* __restrict__ selidx,
    float* __restrict__ agg) {
  __shared__ short WT[PD * LSTRIDE];
  __shared__ float red[PD];
  int tid = threadIdx.x;
  stage_wt(sparse_w, WT, tid);
  if (tid < PD) red[tid] = 0.f;
  __syncthreads();

  int lane = tid & 63, wid = tid >> 6;
  int ln = lane & 15, quad = lane >> 4;
  int b  = blockIdx.x >> 5;            // 32 row-blocks per batch
  int rb = blockIdx.x & 31;
  int j  = rb * 64 + wid * 16 + ln;    // selected slot
  int row = selidx[(size_t)b * PK + j];

  const float* ap = x + ((size_t)b * PL + row) * PC + quad * 8;
  bf16x8 a0 = load_a8(ap);
  bf16x8 a1 = load_a8(ap + 32);

  f32x4 acc[8];
  #pragma unroll
  for (int t = 0; t < 8; ++t) acc[t] = (f32x4){0.f, 0.f, 0.f, 0.f};

  #pragma unroll
  for (int t = 0; t < 8; ++t) {
    const short* wp = WT + (t * 16 + ln) * LSTRIDE + quad * 8;
    bf16x8 b0 = *(const bf16x8*)wp;
    bf16x8 b1 = *(const bf16x8*)(wp + 32);
    acc[t] = __builtin_amdgcn_mfma_f32_16x16x32_bf16(a0, b0, acc[t], 0, 0, 0);
    acc[t] = __builtin_amdgcn_mfma_f32_16x16x32_bf16(a1, b1, acc[t], 0, 0, 0);
  }

  // gelu(feat + bias), sum over this wave's 16 rows per column
  #pragma unroll
  for (int t = 0; t < 8; ++t) {
    float bias = sparse_b[t * 16 + ln];
    float s = 0.f;
    #pragma unroll
    for (int i = 0; i < 4; ++i) {
      float v = acc[t][i] + bias;
      s += 0.5f * v * (1.0f + erff(v * 0.70710678118654752f));
    }
    s += __shfl_xor(s, 16);
    s += __shfl_xor(s, 32);     // now sum over all 16 rows of the wave
    if (quad == 0) atomicAdd(&red[t * 16 + ln], s);
  }
  __syncthreads();
  if (tid < PD) atomicAdd(&agg[(size_t)b * PD + tid], red[tid]);
}

// ---------------- kernel 4: full GEMM + agg + LayerNorm + store -------------
__global__ __launch_bounds__(256) void full_ln_kernel(
    const float* __restrict__ x, const float* __restrict__ full_w,
    const float* __restrict__ full_b, const float* __restrict__ ln_g,
    const float* __restrict__ ln_b, const float* __restrict__ agg,
    float* __restrict__ out) {
  __shared__ short WT[PD * LSTRIDE];
  int tid = threadIdx.x;
  stage_wt(full_w, WT, tid);
  __syncthreads();

  int lane = tid & 63, wid = tid >> 6;
  int ln = lane & 15, quad = lane >> 4;
  int rowbase = blockIdx.x * 64 + wid * 16;   // 16 rows per wave
  int b = rowbase >> 12;                       // L = 4096

  const float invK = 1.0f / (float)PK;
  float bias[8], gg[8], bb[8];
  #pragma unroll
  for (int t = 0; t < 8; ++t) {
    int d = t * 16 + ln;
    bias[t] = full_b[d] + agg[(size_t)b * PD + d] * invK;
    gg[t] = ln_g[d];
    bb[t] = ln_b[d];
  }

  int arow = rowbase + ln;
  const float* ap = x + (size_t)arow * PC + quad * 8;
  bf16x8 a0 = load_a8(ap);
  bf16x8 a1 = load_a8(ap + 32);

  f32x4 acc[8];
  #pragma unroll
  for (int t = 0; t < 8; ++t) acc[t] = (f32x4){0.f, 0.f, 0.f, 0.f};

  #pragma unroll
  for (int t = 0; t < 8; ++t) {
    const short* wp = WT + (t * 16 + ln) * LSTRIDE + quad * 8;
    bf16x8 b0 = *(const bf16x8*)wp;
    bf16x8 b1 = *(const bf16x8*)(wp + 32);
    acc[t] = __builtin_amdgcn_mfma_f32_16x16x32_bf16(a0, b0, acc[t], 0, 0, 0);
    acc[t] = __builtin_amdgcn_mfma_f32_16x16x32_bf16(a1, b1, acc[t], 0, 0, 0);
  }

  // h = feat + bias; LayerNorm per row (row = rowbase + quad*4 + i,
  // its 128 cols live on the 16 lanes of this quad x 8 tiles)
  float s[4] = {0.f, 0.f, 0.f, 0.f}, ss[4] = {0.f, 0.f, 0.f, 0.f};
  #pragma unroll
  for (int t = 0; t < 8; ++t) {
    #pragma unroll
    for (int i = 0; i < 4; ++i) {
      float h = acc[t][i] + bias[t];
      acc[t][i] = h;
      s[i] += h;
      ss[i] += h * h;
    }
  }
  #pragma unroll
  for (int i = 0; i < 4; ++i) {
    #pragma unroll
    for (int off = 1; off < 16; off <<= 1) {
      s[i]  += __shfl_xor(s[i], off);
      ss[i] += __shfl_xor(ss[i], off);
    }
  }
  float mu[4], inv[4];
  #pragma unroll
  for (int i = 0; i < 4; ++i) {
    mu[i] = s[i] * (1.0f / 128.0f);
    float var = ss[i] * (1.0f / 128.0f) - mu[i] * mu[i];
    inv[i] = rsqrtf(var + 1e-5f);
  }
  #pragma unroll
  for (int t = 0; t < 8; ++t) {
    #pragma unroll
    for (int i = 0; i < 4; ++i) {
      int r = rowbase + quad * 4 + i;
      out[(size_t)r * PD + t * 16 + ln] = (acc[t][i] - mu[i]) * inv[i] * gg[t] + bb[t];
    }
  }
}

// ---------------- launcher ----------------
extern "C" void kernel_launch(void* const* d_in, const int* in_sizes, int n_in,
                              void* d_out, int out_size, void* d_ws, size_t ws_size,
                              hipStream_t stream) {
  const float* x        = (const float*)d_in[0];
  const float* score_w  = (const float*)d_in[1];
  const float* score_b  = (const float*)d_in[2];
  const float* sparse_w = (const float*)d_in[3];
  const float* sparse_b = (const float*)d_in[4];
  const float* full_w   = (const float*)d_in[5];
  const float* full_b   = (const float*)d_in[6];
  const float* ln_g     = (const float*)d_in[7];
  const float* ln_b     = (const float*)d_in[8];
  float* out = (float*)d_out;

  float* scores = (float*)d_ws;                                  // B*L f32
  int*   selidx = (int*)((char*)d_ws + (size_t)PB * PL * 4);     // B*K i32
  float* agg    = (float*)((char*)d_ws + (size_t)PB * PL * 4 + (size_t)PB * PK * 4); // B*D f32

  scores_kernel<<<PB * PL / 16, 256, 0, stream>>>(x, score_w, score_b, scores);
  select_kernel<<<PB, 256, 0, stream>>>(scores, selidx, agg);
  sparse_kernel<<<PB * (PK / 64), 256, 0, stream>>>(x, sparse_w, sparse_b, selidx, agg);
  full_ln_kernel<<<PB * PL / 64, 256, 0, stream>>>(x, full_w, full_b, ln_g, ln_b, agg, out);
}

// Round 4
// 135.770 us; speedup vs baseline: 1.3594x; 1.0173x over previous
//
#include <hip/hip_runtime.h>
#include <math.h>

// Problem constants
static constexpr int PB = 32;      // batch
static constexpr int PL = 4096;    // seq len
static constexpr int PC = 64;      // in channels
static constexpr int PD = 128;     // out channels
static constexpr int PK = 2048;    // TOPK = L/2

typedef __attribute__((ext_vector_type(8))) short bf16x8;
typedef __attribute__((ext_vector_type(4))) float f32x4;

static constexpr int LSTRIDE = 72; // halfwords per row in LDS W^T (pad 64 -> 72, keeps 16B align)

__device__ inline short f2bf(float f) {
  unsigned u = __float_as_uint(f);
  u += 0x7FFFu + ((u >> 16) & 1u);   // RNE
  return (short)(u >> 16);
}

__device__ inline bf16x8 load_a8(const float* p) {
  float4 f0 = *(const float4*)p;
  float4 f1 = *(const float4*)(p + 4);
  bf16x8 r;
  r[0] = f2bf(f0.x); r[1] = f2bf(f0.y); r[2] = f2bf(f0.z); r[3] = f2bf(f0.w);
  r[4] = f2bf(f1.x); r[5] = f2bf(f1.y); r[6] = f2bf(f1.z); r[7] = f2bf(f1.w);
  return r;
}

// ---------------- kernel 1: scores (B,L) ----------------
// float4 loads (16 B/lane). Block = 256 threads = 16 rows;
// thread tid: row r = tid>>4, channel-quad c4 = tid&15.
__global__ __launch_bounds__(256) void scores_kernel(
    const float* __restrict__ x, const float* __restrict__ score_w,
    const float* __restrict__ score_b, float* __restrict__ scores) {
  int tid = threadIdx.x;
  int r  = tid >> 4;
  int c4 = tid & 15;
  int row = blockIdx.x * 16 + r;                 // grid covers B*L/16 exactly
  float4 xv = *(const float4*)(x + (size_t)row * PC + c4 * 4);
  float4 wv = *(const float4*)(score_w + c4 * 4);
  float v = xv.x * wv.x + xv.y * wv.y + xv.z * wv.z + xv.w * wv.w;
  #pragma unroll
  for (int off = 1; off < 16; off <<= 1) v += __shfl_xor(v, off);
  if (c4 == 0) scores[row] = v + score_b[0];
}

// ---------------- kernel 2: exact top-K selection per batch ----------------
// one block (256 threads = 4 waves) per batch; radix-select over sortable uint
// keys, ties at threshold broken by lowest index (matches lax.top_k).
// R4: keys live in 16 VGPRs per thread for the WHOLE kernel (no keys LDS
// array, no ds_read in the rounds); histogram split per-wave (4 copies) to
// cut same-bucket atomic serialization ~4x. Also zeroes agg[b*D..].
__global__ __launch_bounds__(256) void select_kernel(
    const float* __restrict__ scores, int* __restrict__ selidx,
    float* __restrict__ agg) {
  __shared__ unsigned hist4[4 * 256];   // per-wave histograms, 4 KB
  __shared__ unsigned sbuf[257];
  __shared__ unsigned wsum[4];
  __shared__ unsigned sh_prefix, sh_need;

  int tid = threadIdx.x;
  int lane = tid & 63;
  int wid  = tid >> 6;
  int b = blockIdx.x;
  const float* sc = scores + (size_t)b * PL;

  // stage 16 keys into registers (4 coalesced float4 loads)
  unsigned k[16];
  #pragma unroll
  for (int q = 0; q < 4; ++q) {
    float4 f = *(const float4*)(sc + tid * 16 + q * 4);
    unsigned u0 = __float_as_uint(f.x), u1 = __float_as_uint(f.y);
    unsigned u2 = __float_as_uint(f.z), u3 = __float_as_uint(f.w);
    k[q * 4 + 0] = (u0 & 0x80000000u) ? ~u0 : (u0 | 0x80000000u);
    k[q * 4 + 1] = (u1 & 0x80000000u) ? ~u1 : (u1 | 0x80000000u);
    k[q * 4 + 2] = (u2 & 0x80000000u) ? ~u2 : (u2 | 0x80000000u);
    k[q * 4 + 3] = (u3 & 0x80000000u) ? ~u3 : (u3 | 0x80000000u);
  }

  if (tid == 0) { sh_prefix = 0u; sh_need = (unsigned)PK; sbuf[256] = 0u; }
  // zero agg for this batch (sparse_kernel accumulates into it later)
  if (tid < PD) agg[(size_t)b * PD + tid] = 0.f;

  // 4 radix rounds, MSB first
  for (int r = 3; r >= 0; --r) {
    int shift = r * 8;
    #pragma unroll
    for (int w = 0; w < 4; ++w) hist4[w * 256 + tid] = 0u;
    __syncthreads();                      // also publishes sh_prefix/sh_need
    unsigned prefix = sh_prefix;
    unsigned need   = sh_need;
    unsigned maskAbove = (r == 3) ? 0u : (~0u << (shift + 8));
    unsigned* myhist = &hist4[wid * 256];
    #pragma unroll
    for (int j = 0; j < 16; ++j) {
      if ((k[j] & maskAbove) == prefix)
        atomicAdd(&myhist[(k[j] >> shift) & 255u], 1u);
    }
    __syncthreads();
    // merge 4 copies + inclusive suffix sum via wave shfl (bucket = tid)
    unsigned v = hist4[tid] + hist4[256 + tid] + hist4[512 + tid] + hist4[768 + tid];
    #pragma unroll
    for (int off = 1; off < 64; off <<= 1) {
      unsigned t = __shfl_down(v, off);
      if (lane + off < 64) v += t;
    }
    if (lane == 0) wsum[wid] = v;         // sum of this wave's 64 buckets
    __syncthreads();
    unsigned add = 0;
    #pragma unroll
    for (int w = 0; w < 4; ++w) if (w > wid) add += wsum[w];
    sbuf[tid] = v + add;
    __syncthreads();
    // suffix non-increasing; unique boundary: sbuf[d]>=need, sbuf[d+1]<need
    if (sbuf[tid] >= need && sbuf[tid + 1] < need) {
      sh_prefix = prefix | ((unsigned)tid << shift);
      sh_need = need - sbuf[tid + 1];
    }
  }
  __syncthreads();
  unsigned T = sh_prefix;       // K-th largest key
  unsigned needEq = sh_need;    // how many ==T to take (lowest indices)

  // each thread owns 16 contiguous indices (base = tid*16), keys in regs
  int base = tid * 16;
  unsigned ceq = 0;
  #pragma unroll
  for (int j = 0; j < 16; ++j) ceq += (k[j] == T);

  // exclusive prefix scan of eq counts (wave shfl + cross-wave)
  unsigned v1 = ceq;
  #pragma unroll
  for (int off = 1; off < 64; off <<= 1) {
    unsigned t = __shfl_up(v1, off);
    if (lane >= off) v1 += t;
  }
  if (lane == 63) wsum[wid] = v1;
  __syncthreads();
  unsigned add1 = 0;
  #pragma unroll
  for (int w = 0; w < 4; ++w) if (w < wid) add1 += wsum[w];
  unsigned eqbase = v1 + add1 - ceq;
  __syncthreads();                        // protect wsum before reuse

  // count selected in my chunk
  unsigned csel = 0, eqr = eqbase;
  #pragma unroll
  for (int j = 0; j < 16; ++j) {
    if (k[j] > T) csel++;
    else if (k[j] == T) { if (eqr < needEq) csel++; eqr++; }
  }
  unsigned v2 = csel;
  #pragma unroll
  for (int off = 1; off < 64; off <<= 1) {
    unsigned t = __shfl_up(v2, off);
    if (lane >= off) v2 += t;
  }
  if (lane == 63) wsum[wid] = v2;
  __syncthreads();
  unsigned add2 = 0;
  #pragma unroll
  for (int w = 0; w < 4; ++w) if (w < wid) add2 += wsum[w];
  unsigned pos = v2 + add2 - csel;

  // write compacted indices
  eqr = eqbase;
  int* outp = selidx + (size_t)b * PK;
  #pragma unroll
  for (int j = 0; j < 16; ++j) {
    bool sel;
    if (k[j] > T) sel = true;
    else if (k[j] == T) { sel = (eqr < needEq); eqr++; }
    else sel = false;
    if (sel) outp[pos++] = base + j;
  }
}

// ---------------- shared staging: W^T (C x D fp32) -> LDS bf16 [D][LSTRIDE] ----
__device__ inline void stage_wt(const float* __restrict__ w, short* WT, int tid) {
  // 4096 c-pairs: i -> d = i&127, cpair = i>>7
  for (int i = tid; i < (PC / 2) * PD; i += 256) {
    int d = i & (PD - 1);
    int cp = i >> 7;
    float a = w[(size_t)(2 * cp) * PD + d];
    float c = w[(size_t)(2 * cp + 1) * PD + d];
    unsigned lo = (unsigned short)f2bf(a);
    unsigned hi = (unsigned short)f2bf(c);
    ((unsigned*)WT)[d * (LSTRIDE / 2) + cp] = lo | (hi << 16);
  }
}

// ---------------- kernel 3: sparse GEMM + gelu + sum into agg ----------------
// block = 256 = 4 waves; each wave: 16 selected rows x 128 cols via MFMA
__global__ __launch_bounds__(256) void sparse_kernel(
    const float* __restrict__ x, const float* __restrict__ sparse_w,
    const float* __restrict__ sparse_b, const int* __restrict__ selidx,
    float* __restrict__ agg) {
  __shared__ short WT[PD * LSTRIDE];
  __shared__ float red[PD];
  int tid = threadIdx.x;
  stage_wt(sparse_w, WT, tid);
  if (tid < PD) red[tid] = 0.f;
  __syncthreads();

  int lane = tid & 63, wid = tid >> 6;
  int ln = lane & 15, quad = lane >> 4;
  int b  = blockIdx.x >> 5;            // 32 row-blocks per batch
  int rb = blockIdx.x & 31;
  int j  = rb * 64 + wid * 16 + ln;    // selected slot
  int row = selidx[(size_t)b * PK + j];

  const float* ap = x + ((size_t)b * PL + row) * PC + quad * 8;
  bf16x8 a0 = load_a8(ap);
  bf16x8 a1 = load_a8(ap + 32);

  f32x4 acc[8];
  #pragma unroll
  for (int t = 0; t < 8; ++t) acc[t] = (f32x4){0.f, 0.f, 0.f, 0.f};

  #pragma unroll
  for (int t = 0; t < 8; ++t) {
    const short* wp = WT + (t * 16 + ln) * LSTRIDE + quad * 8;
    bf16x8 b0 = *(const bf16x8*)wp;
    bf16x8 b1 = *(const bf16x8*)(wp + 32);
    acc[t] = __builtin_amdgcn_mfma_f32_16x16x32_bf16(a0, b0, acc[t], 0, 0, 0);
    acc[t] = __builtin_amdgcn_mfma_f32_16x16x32_bf16(a1, b1, acc[t], 0, 0, 0);
  }

  // gelu(feat + bias), sum over this wave's 16 rows per column
  #pragma unroll
  for (int t = 0; t < 8; ++t) {
    float bias = sparse_b[t * 16 + ln];
    float s = 0.f;
    #pragma unroll
    for (int i = 0; i < 4; ++i) {
      float v = acc[t][i] + bias;
      s += 0.5f * v * (1.0f + erff(v * 0.70710678118654752f));
    }
    s += __shfl_xor(s, 16);
    s += __shfl_xor(s, 32);     // now sum over all 16 rows of the wave
    if (quad == 0) atomicAdd(&red[t * 16 + ln], s);
  }
  __syncthreads();
  if (tid < PD) atomicAdd(&agg[(size_t)b * PD + tid], red[tid]);
}

// ---------------- kernel 4: full GEMM + agg + LayerNorm + store -------------
__global__ __launch_bounds__(256) void full_ln_kernel(
    const float* __restrict__ x, const float* __restrict__ full_w,
    const float* __restrict__ full_b, const float* __restrict__ ln_g,
    const float* __restrict__ ln_b, const float* __restrict__ agg,
    float* __restrict__ out) {
  __shared__ short WT[PD * LSTRIDE];
  int tid = threadIdx.x;
  stage_wt(full_w, WT, tid);
  __syncthreads();

  int lane = tid & 63, wid = tid >> 6;
  int ln = lane & 15, quad = lane >> 4;
  int rowbase = blockIdx.x * 64 + wid * 16;   // 16 rows per wave
  int b = rowbase >> 12;                       // L = 4096

  const float invK = 1.0f / (float)PK;
  float bias[8], gg[8], bb[8];
  #pragma unroll
  for (int t = 0; t < 8; ++t) {
    int d = t * 16 + ln;
    bias[t] = full_b[d] + agg[(size_t)b * PD + d] * invK;
    gg[t] = ln_g[d];
    bb[t] = ln_b[d];
  }

  int arow = rowbase + ln;
  const float* ap = x + (size_t)arow * PC + quad * 8;
  bf16x8 a0 = load_a8(ap);
  bf16x8 a1 = load_a8(ap + 32);

  f32x4 acc[8];
  #pragma unroll
  for (int t = 0; t < 8; ++t) acc[t] = (f32x4){0.f, 0.f, 0.f, 0.f};

  #pragma unroll
  for (int t = 0; t < 8; ++t) {
    const short* wp = WT + (t * 16 + ln) * LSTRIDE + quad * 8;
    bf16x8 b0 = *(const bf16x8*)wp;
    bf16x8 b1 = *(const bf16x8*)(wp + 32);
    acc[t] = __builtin_amdgcn_mfma_f32_16x16x32_bf16(a0, b0, acc[t], 0, 0, 0);
    acc[t] = __builtin_amdgcn_mfma_f32_16x16x32_bf16(a1, b1, acc[t], 0, 0, 0);
  }

  // h = feat + bias; LayerNorm per row (row = rowbase + quad*4 + i,
  // its 128 cols live on the 16 lanes of this quad x 8 tiles)
  float s[4] = {0.f, 0.f, 0.f, 0.f}, ss[4] = {0.f, 0.f, 0.f, 0.f};
  #pragma unroll
  for (int t = 0; t < 8; ++t) {
    #pragma unroll
    for (int i = 0; i < 4; ++i) {
      float h = acc[t][i] + bias[t];
      acc[t][i] = h;
      s[i] += h;
      ss[i] += h * h;
    }
  }
  #pragma unroll
  for (int i = 0; i < 4; ++i) {
    #pragma unroll
    for (int off = 1; off < 16; off <<= 1) {
      s[i]  += __shfl_xor(s[i], off);
      ss[i] += __shfl_xor(ss[i], off);
    }
  }
  float mu[4], inv[4];
  #pragma unroll
  for (int i = 0; i < 4; ++i) {
    mu[i] = s[i] * (1.0f / 128.0f);
    float var = ss[i] * (1.0f / 128.0f) - mu[i] * mu[i];
    inv[i] = rsqrtf(var + 1e-5f);
  }
  #pragma unroll
  for (int t = 0; t < 8; ++t) {
    #pragma unroll
    for (int i = 0; i < 4; ++i) {
      int r = rowbase + quad * 4 + i;
      out[(size_t)r * PD + t * 16 + ln] = (acc[t][i] - mu[i]) * inv[i] * gg[t] + bb[t];
    }
  }
}

// ---------------- launcher ----------------
extern "C" void kernel_launch(void* const* d_in, const int* in_sizes, int n_in,
                              void* d_out, int out_size, void* d_ws, size_t ws_size,
                              hipStream_t stream) {
  const float* x        = (const float*)d_in[0];
  const float* score_w  = (const float*)d_in[1];
  const float* score_b  = (const float*)d_in[2];
  const float* sparse_w = (const float*)d_in[3];
  const float* sparse_b = (const float*)d_in[4];
  const float* full_w   = (const float*)d_in[5];
  const float* full_b   = (const float*)d_in[6];
  const float* ln_g     = (const float*)d_in[7];
  const float* ln_b     = (const float*)d_in[8];
  float* out = (float*)d_out;

  float* scores = (float*)d_ws;                                  // B*L f32
  int*   selidx = (int*)((char*)d_ws + (size_t)PB * PL * 4);     // B*K i32
  float* agg    = (float*)((char*)d_ws + (size_t)PB * PL * 4 + (size_t)PB * PK * 4); // B*D f32

  scores_kernel<<<PB * PL / 16, 256, 0, stream>>>(x, score_w, score_b, scores);
  select_kernel<<<PB, 256, 0, stream>>>(scores, selidx, agg);
  sparse_kernel<<<PB * (PK / 64), 256, 0, stream>>>(x, sparse_w, sparse_b, selidx, agg);
  full_ln_kernel<<<PB * PL / 64, 256, 0, stream>>>(x, full_w, full_b, ln_g, ln_b, agg, out);
}